// Round 10
// baseline (102.755 us; speedup 1.0000x reference)
//
#include <hip/hip_runtime.h>
#include <stdint.h>

#define NLOC 469
#define NCLS 80
#define NFLAT 37520
#define TOPK 1000
#define NWORD 16         // 1000 bits -> 16 u64 words
#define NBIN 32768       // 15-bit histogram over key top bits
#define CAP 2048         // candidate capacity (LDS)

typedef unsigned long long u64;

__device__ __forceinline__ float sigm(float x) { return 1.0f / (1.0f + expf(-x)); }

// order-preserving float -> uint32 (greater float => greater uint)
__device__ __forceinline__ uint32_t f2o(float f) {
    uint32_t u = __float_as_uint(f);
    return (u & 0x80000000u) ? ~u : (u | 0x80000000u);
}

// ------------------------------------------- decode + global histogram
__global__ void decode_kernel(
    const float* __restrict__ s0, const float* __restrict__ l0, const float* __restrict__ c0,
    const float* __restrict__ s1, const float* __restrict__ l1, const float* __restrict__ c1,
    const float* __restrict__ s2, const float* __restrict__ l2, const float* __restrict__ c2,
    u64* __restrict__ keys, float4* __restrict__ bbox, unsigned short* __restrict__ bin16,
    int* __restrict__ hist)
{
    int t = blockIdx.x * blockDim.x + threadIdx.x;
    if (t < NFLAT) {
        int p = t / NCLS;
        int k = t - p * NCLS;
        int c = k + 1;                       // class channel (0 = background, dropped)
        const float* sr; const float* cr; int local, hw;
        if (p < 350)      { sr = s0; cr = c0; local = p;       hw = 350; }
        else if (p < 441) { sr = s1; cr = c1; local = p - 350; hw = 91;  }
        else              { sr = s2; cr = c2; local = p - 441; hw = 28;  }
        float val = sqrtf(sigm(sr[c * hw + local]) * sigm(cr[local]));
        float masked = (val >= 0.05f) ? val : -1.0f;
        // key: value-major, tie -> lower index wins (larger low word)
        u64 key = ((u64)f2o(masked) << 32) | (u64)(0xFFFFFFFFu - (uint32_t)t);
        keys[t] = key;
        int b = (int)(key >> 49);
        bin16[t] = (unsigned short)b;
        atomicAdd(&hist[b], 1);              // parallel global hist (memset'd upstream)
    }
    if (t < NLOC) {
        int p = t;
        const float* lr; int local, hw, w; float is;
        if (p < 350)      { lr = l0; local = p;       hw = 350; w = 25; is = 16.0f; }
        else if (p < 441) { lr = l1; local = p - 350; hw = 91;  w = 13; is = 32.0f; }
        else              { lr = l2; local = p - 441; hw = 28;  w = 7;  is = 64.0f; }
        int y = local / w, x = local - y * w;
        float px = ((float)x + 0.5f) * is;
        float py = ((float)y + 0.5f) * is;
        float L = lr[local] * is;
        float T = lr[hw + local] * is;
        float R = lr[2 * hw + local] * is;
        float B = lr[3 * hw + local] * is;
        bbox[p] = make_float4(px - L, py - T, px + R, py + B);
    }
}

// --------------------- top-k select: prebuilt hist, scatter, segment rank
__global__ void __launch_bounds__(1024, 4) topk_kernel(
    const u64* __restrict__ keys, const unsigned short* __restrict__ bin16,
    const int* __restrict__ hist,
    float* __restrict__ top_val, int* __restrict__ top_idx)
{
    __shared__ int histL[NBIN];      // 128 KB: start offsets -> end cursors
    __shared__ int wsum[16];
    __shared__ u64 candL[CAP];       // 16 KB, bin-segmented after scatter
    __shared__ int bstar_s;
    int tid = threadIdx.x;
    int lane = tid & 63, wv = tid >> 6;
    // thread tid owns bins [base, base+32); tid=0 owns the HIGHEST bins
    int base = NBIN - 32 * (tid + 1);
    int r[32];
    int gsum = 0;
    #pragma unroll
    for (int k = 0; k < 32; ++k) { r[k] = hist[base + k]; gsum += r[k]; }
    // two-level inclusive scan over 1024 gsums
    int ws = gsum;
    #pragma unroll
    for (int d = 1; d < 64; d <<= 1) {
        int v = __shfl_up(ws, d, 64);
        if (lane >= d) ws += v;
    }
    if (lane == 63) wsum[wv] = ws;
    __syncthreads();
    if (tid < 16) {
        int v = wsum[tid];
        int sc = v;
        #pragma unroll
        for (int d = 1; d < 16; d <<= 1) {
            int u2 = __shfl_up(sc, d, 64);
            if (tid >= d) sc += u2;
        }
        wsum[tid] = sc - v;                  // exclusive wave prefix
    }
    __syncthreads();
    int incl = ws + wsum[wv];
    int cumAbove = incl - gsum;   // keys in bins above my range
    if (cumAbove < TOPK && incl >= TOPK) {       // exactly one thread crosses
        int running = cumAbove;
        #pragma unroll
        for (int k = 31; k >= 0; --k) {          // walk own bins descending (regs)
            if (running + r[k] >= TOPK) { bstar_s = base + k; break; }
            running += r[k];
        }
    }
    // write start offsets (descending bin-major layout)
    {
        int run = cumAbove;
        #pragma unroll
        for (int k = 31; k >= 0; --k) { histL[base + k] = run; run += r[k]; }
    }
    __syncthreads();
    int Bstar = bstar_s;
    // counting-sort scatter: cursors turn start(b) into end(b)
    const uint32_t* b2 = (const uint32_t*)bin16;
    for (int t = tid; t < NFLAT / 2; t += 1024) {
        uint32_t v = b2[t];
        int b0 = (int)(v & 0xffffu), b1 = (int)(v >> 16);
        if (b0 >= Bstar) {
            int pos = atomicAdd(&histL[b0], 1);
            if (pos < CAP) candL[pos] = keys[2 * t];
        }
        if (b1 >= Bstar) {
            int pos = atomicAdd(&histL[b1], 1);
            if (pos < CAP) candL[pos] = keys[2 * t + 1];
        }
    }
    __syncthreads();
    int C = min(histL[Bstar], CAP);   // end(Bstar) == total candidate count
    // exact rank = segL (#cands in higher bins) + within-segment count
    for (int p = tid; p < C; p += 1024) {
        u64 k = candL[p];
        int b = (int)(k >> 49);
        int segL = (b == NBIN - 1) ? 0 : min(histL[b + 1], CAP);
        int segR = min(histL[b], CAP);
        int cnt = segL;
        for (int q = segL; q < segR; ++q)
            cnt += (candL[q] > k) ? 1 : 0;
        if (cnt < TOPK) {
            uint32_t o = (uint32_t)(k >> 32);
            uint32_t u = (o & 0x80000000u) ? (o ^ 0x80000000u) : ~o;  // inverse f2o
            top_val[cnt] = __uint_as_float(u);
            top_idx[cnt] = (int)(0xFFFFFFFFu - (uint32_t)(k & 0xFFFFFFFFu));
        }
    }
}

// --------------------------- per-block redundant prep + suppression matrix
__global__ void maskprep_kernel(const int* __restrict__ top_idx,
                                const float4* __restrict__ bbox,
                                u64* __restrict__ mask)
{
    __shared__ float4 sboxL[TOPK];   // 16000 B
    __shared__ float sareaL[TOPK];
    __shared__ int   labL[TOPK];
    __shared__ float redL[4];
    int tid = threadIdx.x;
    float m = -3.0e38f;
    for (int j = tid; j < TOPK; j += 256) {
        int idx = top_idx[j];
        int p = idx / NCLS;
        int lab = idx - p * NCLS;
        float4 b = bbox[p];
        sboxL[j] = b; labL[j] = lab;
        m = fmaxf(m, fmaxf(fmaxf(b.x, b.y), fmaxf(b.z, b.w)));
    }
    for (int o = 32; o > 0; o >>= 1) m = fmaxf(m, __shfl_down(m, o, 64));
    if ((tid & 63) == 0) redL[tid >> 6] = m;
    __syncthreads();
    float Mp1 = fmaxf(fmaxf(redL[0], redL[1]), fmaxf(redL[2], redL[3])) + 1.0f;
    for (int j = tid; j < TOPK; j += 256) {
        float off = (float)labL[j] * Mp1;
        float4 b = sboxL[j];
        float4 s = make_float4(b.x + off, b.y + off, b.z + off, b.w + off);
        sboxL[j] = s;
        sareaL[j] = fmaxf(s.z - s.x, 0.f) * fmaxf(s.w - s.y, 0.f);
    }
    __syncthreads();
    int g = blockIdx.x * 256 + tid;
    if (g < TOPK * NWORD) {
        int i = g >> 4, w = g & 15;
        float4 si = sboxL[i]; float ai = sareaL[i];
        int j0 = w * 64, j1 = min(j0 + 64, TOPK);
        u64 bits = 0;
        for (int j = max(j0, i + 1); j < j1; ++j) {
            float4 sj = sboxL[j];
            float ltx = fmaxf(si.x, sj.x), lty = fmaxf(si.y, sj.y);
            float rbx = fminf(si.z, sj.z), rby = fminf(si.w, sj.w);
            float iw = fmaxf(rbx - ltx, 0.f), ih = fmaxf(rby - lty, 0.f);
            float inter = iw * ih;
            float iou = inter / fmaxf(ai + sareaL[j] - inter, 1e-9f);
            if (iou > 0.6f) bits |= 1ull << (j - j0);
        }
        mask[g] = bits;
    }
}

// ---- greedy scan, sparsity-aware: only rows with outgoing edges processed.
// Freeze property: mask[i] has only bits j>i, so avail bit b is final once all
// rows < b are done -> skeep[word] = avail at end of word; zero rows are no-ops.
__global__ void __launch_bounds__(1024, 4) scan_out_kernel(
    const u64* __restrict__ mask,
    const float* __restrict__ top_val, const int* __restrict__ top_idx,
    const float4* __restrict__ bbox, float* __restrict__ out)
{
    __shared__ uint32_t smask[1024 * 32];   // 131072 B; rows 1000..1023 zeroed
    __shared__ uint32_t skeep32[32];
    __shared__ uint32_t validw32[32];
    __shared__ uint32_t zmaskL[32];
    int tid = threadIdx.x;
    int lane64 = tid & 63, wv = tid >> 6;
    float tv = (tid < TOPK) ? top_val[tid] : -1.0f;
    u64 bal = __ballot(tid < TOPK && tv >= 0.05f);
    if (lane64 == 0) {
        validw32[wv * 2]     = (uint32_t)bal;
        validw32[wv * 2 + 1] = (uint32_t)(bal >> 32);
    }
    u64* smask64 = (u64*)smask;
    for (int g = tid; g < 1024 * NWORD; g += 1024)
        smask64[g] = (g < TOPK * NWORD) ? mask[g] : 0ull;
    __syncthreads();
    // per-row nonzero flags (rotated word order -> conflict-free)
    {
        uint32_t orv = 0;
        #pragma unroll
        for (int w = 0; w < 32; ++w) orv |= smask[tid * 32 + ((w + tid) & 31)];
        u64 zb = __ballot(orv != 0u);    // rows >=1000 are zero -> flag false
        if (lane64 == 0) {
            zmaskL[wv * 2]     = (uint32_t)zb;
            zmaskL[wv * 2 + 1] = (uint32_t)(zb >> 32);
        }
    }
    __syncthreads();
    if (tid < 32) {
        const int lane = tid;              // owns u32 word `lane` of the 1024-bit state
        uint32_t vwreg = validw32[lane];
        uint32_t zreg  = zmaskL[lane];
        uint32_t sup = 0;                  // suppressed bits, word `lane`
        for (int wc = 0; wc < 32; ++wc) {
            uint32_t nzw = (uint32_t)__builtin_amdgcn_readlane((int)zreg, wc);
            uint32_t avail = (uint32_t)__builtin_amdgcn_readlane((int)vwreg, wc)
                           & ~(uint32_t)__builtin_amdgcn_readlane((int)sup, wc);
            // 3-deep rotating prefetch over set bits (rows with outgoing edges)
            int p0 = -1, p1 = -1, p2 = -1;
            uint32_t R0 = 0, R1 = 0, R2 = 0;
            if (nzw) { p0 = __ffs(nzw) - 1; nzw &= nzw - 1;
                       R0 = smask[(wc * 32 + p0) * 32 + lane]; }
            if (nzw) { p1 = __ffs(nzw) - 1; nzw &= nzw - 1;
                       R1 = smask[(wc * 32 + p1) * 32 + lane]; }
            if (nzw) { p2 = __ffs(nzw) - 1; nzw &= nzw - 1;
                       R2 = smask[(wc * 32 + p2) * 32 + lane]; }
            while (p0 >= 0) {
                uint32_t rc = (uint32_t)__builtin_amdgcn_readlane((int)R0, wc);
                uint32_t kp = (avail >> p0) & 1u;
                uint32_t mm = 0u - kp;
                sup   |= R0 & mm;
                avail &= ~(rc & mm);
                p0 = p1; R0 = R1; p1 = p2; R1 = R2;
                if (nzw) { p2 = __ffs(nzw) - 1; nzw &= nzw - 1;
                           R2 = smask[(wc * 32 + p2) * 32 + lane]; }
                else p2 = -1;
            }
            if (lane == 0) skeep32[wc] = avail;   // frozen == final keep bits
        }
    }
    __syncthreads();
    int j = tid;
    if (j < TOPK) {
        int idx = top_idx[j];
        int p = idx / NCLS;
        int lab = idx - p * NCLS;
        float4 b = bbox[p];
        bool kp = (skeep32[j >> 5] >> (j & 31)) & 1u;
        float x1 = fminf(fmaxf(b.x, 0.f), 224.f);
        float y1 = fminf(fmaxf(b.y, 0.f), 398.f);
        float x2 = fminf(fmaxf(b.z, 0.f), 224.f);
        float y2 = fminf(fmaxf(b.w, 0.f), 398.f);
        kp = kp && ((x2 - x1) >= 1e-5f) && ((y2 - y1) >= 1e-5f);
        out[j * 4 + 0] = kp ? x1 : 0.f;
        out[j * 4 + 1] = kp ? y1 : 0.f;
        out[j * 4 + 2] = kp ? x2 : 0.f;
        out[j * 4 + 3] = kp ? y2 : 0.f;
        out[4 * TOPK + j] = kp ? tv : -1.0f;
        out[5 * TOPK + j] = (float)lab;
        out[6 * TOPK + j] = kp ? 1.0f : 0.0f;
    }
}

extern "C" void kernel_launch(void* const* d_in, const int* in_sizes, int n_in,
                              void* d_out, int out_size, void* d_ws, size_t ws_size,
                              hipStream_t stream)
{
    const float* s0 = (const float*)d_in[0];
    const float* l0 = (const float*)d_in[1];
    const float* c0 = (const float*)d_in[2];
    const float* s1 = (const float*)d_in[3];
    const float* l1 = (const float*)d_in[4];
    const float* c1 = (const float*)d_in[5];
    const float* s2 = (const float*)d_in[6];
    const float* l2 = (const float*)d_in[7];
    const float* c2 = (const float*)d_in[8];

    uint8_t* ws = (uint8_t*)d_ws;
    u64*    keys = (u64*)   (ws);              // 37520*8  = 300160 B
    float4* bbox = (float4*)(ws + 300160);     // 469*16   =   7504 B
    int*    hist = (int*)   (ws + 307664);     // 32768*4  = 131072 B (dead after topk)
    u64*    mask = (u64*)   (ws + 307664);     // aliases hist: 16000*8 = 128000 B
    float*  tval = (float*) (ws + 438736);     // 1000*4
    int*    tidx = (int*)   (ws + 442736);     // 1000*4
    unsigned short* bin16 = (unsigned short*)(ws + 446736);  // 75040 -> 521776 B total

    hipMemsetAsync(hist, 0, NBIN * sizeof(int), stream);
    decode_kernel<<<dim3((NFLAT + 255) / 256), 256, 0, stream>>>(
        s0, l0, c0, s1, l1, c1, s2, l2, c2, keys, bbox, bin16, hist);
    topk_kernel<<<1, 1024, 0, stream>>>(keys, bin16, hist, tval, tidx);
    maskprep_kernel<<<dim3((TOPK * NWORD + 255) / 256), 256, 0, stream>>>(tidx, bbox, mask);
    scan_out_kernel<<<1, 1024, 0, stream>>>(mask, tval, tidx, bbox, (float*)d_out);
}

// Round 11
// 102.416 us; speedup vs baseline: 1.0033x; 1.0033x over previous
//
#include <hip/hip_runtime.h>
#include <stdint.h>

#define NLOC 469
#define NCLS 80
#define NFLAT 37520
#define TOPK 1000
#define NWORD 16         // 1000 bits -> 16 u64 words
#define NBIN 32768       // 15-bit histogram over key top bits
#define CAP 2048         // candidate capacity (LDS)

typedef unsigned long long u64;

__device__ __forceinline__ float sigm(float x) { return 1.0f / (1.0f + expf(-x)); }

// order-preserving float -> uint32 (greater float => greater uint)
__device__ __forceinline__ uint32_t f2o(float f) {
    uint32_t u = __float_as_uint(f);
    return (u & 0x80000000u) ? ~u : (u | 0x80000000u);
}

// ---------------------------------------------------------------- hist zero
__global__ void zero_hist_kernel(int* __restrict__ hist)
{
    int t = blockIdx.x * blockDim.x + threadIdx.x;
    int4* h4 = (int4*)hist;
    h4[t] = make_int4(0, 0, 0, 0);           // 32 blocks * 256 thr * 4 ints = NBIN
}

// ------------------------------------------- decode + valid-only histogram
__global__ void decode_kernel(
    const float* __restrict__ s0, const float* __restrict__ l0, const float* __restrict__ c0,
    const float* __restrict__ s1, const float* __restrict__ l1, const float* __restrict__ c1,
    const float* __restrict__ s2, const float* __restrict__ l2, const float* __restrict__ c2,
    u64* __restrict__ keys, float4* __restrict__ bbox, unsigned short* __restrict__ bin16,
    int* __restrict__ hist)
{
    int t = blockIdx.x * blockDim.x + threadIdx.x;
    if (t < NFLAT) {
        int p = t / NCLS;
        int k = t - p * NCLS;
        int c = k + 1;                       // class channel (0 = background, dropped)
        const float* sr; const float* cr; int local, hw;
        if (p < 350)      { sr = s0; cr = c0; local = p;       hw = 350; }
        else if (p < 441) { sr = s1; cr = c1; local = p - 350; hw = 91;  }
        else              { sr = s2; cr = c2; local = p - 441; hw = 28;  }
        float val = sqrtf(sigm(sr[c * hw + local]) * sigm(cr[local]));
        bool valid = (val >= 0.05f);
        float masked = valid ? val : -1.0f;
        // key: value-major, tie -> lower index wins (larger low word)
        u64 key = ((u64)f2o(masked) << 32) | (u64)(0xFFFFFFFFu - (uint32_t)t);
        keys[t] = key;
        int b = (int)(key >> 49);
        // sentinel bin 0 for invalid keys: valid bins are >= f2o(0.05)>>17 >> 0,
        // and hist only counts valid keys -> no same-address atomic pileup on -1.0
        bin16[t] = valid ? (unsigned short)b : (unsigned short)0;
        if (valid) atomicAdd(&hist[b], 1);
    }
    if (t < NLOC) {
        int p = t;
        const float* lr; int local, hw, w; float is;
        if (p < 350)      { lr = l0; local = p;       hw = 350; w = 25; is = 16.0f; }
        else if (p < 441) { lr = l1; local = p - 350; hw = 91;  w = 13; is = 32.0f; }
        else              { lr = l2; local = p - 441; hw = 28;  w = 7;  is = 64.0f; }
        int y = local / w, x = local - y * w;
        float px = ((float)x + 0.5f) * is;
        float py = ((float)y + 0.5f) * is;
        float L = lr[local] * is;
        float T = lr[hw + local] * is;
        float R = lr[2 * hw + local] * is;
        float B = lr[3 * hw + local] * is;
        bbox[p] = make_float4(px - L, py - T, px + R, py + B);
    }
}

// --------------------- top-k select: prebuilt hist, scatter, segment rank
__global__ void __launch_bounds__(1024, 4) topk_kernel(
    const u64* __restrict__ keys, const unsigned short* __restrict__ bin16,
    const int* __restrict__ hist,
    float* __restrict__ top_val, int* __restrict__ top_idx)
{
    __shared__ int histL[NBIN];      // 128 KB: start offsets -> end cursors
    __shared__ int wsum[16];
    __shared__ u64 candL[CAP];       // 16 KB, bin-segmented after scatter
    __shared__ int bstar_s;
    int tid = threadIdx.x;
    int lane = tid & 63, wv = tid >> 6;
    // thread tid owns bins [base, base+32); tid=0 owns the HIGHEST bins
    int base = NBIN - 32 * (tid + 1);
    int r[32];
    int gsum = 0;
    #pragma unroll
    for (int k = 0; k < 32; ++k) { r[k] = hist[base + k]; gsum += r[k]; }
    // two-level inclusive scan over 1024 gsums
    int ws = gsum;
    #pragma unroll
    for (int d = 1; d < 64; d <<= 1) {
        int v = __shfl_up(ws, d, 64);
        if (lane >= d) ws += v;
    }
    if (lane == 63) wsum[wv] = ws;
    __syncthreads();
    if (tid < 16) {
        int v = wsum[tid];
        int sc = v;
        #pragma unroll
        for (int d = 1; d < 16; d <<= 1) {
            int u2 = __shfl_up(sc, d, 64);
            if (tid >= d) sc += u2;
        }
        wsum[tid] = sc - v;                  // exclusive wave prefix
    }
    __syncthreads();
    int incl = ws + wsum[wv];
    int cumAbove = incl - gsum;   // valid keys in bins above my range
    if (cumAbove < TOPK && incl >= TOPK) {       // exactly one thread crosses
        int running = cumAbove;
        #pragma unroll
        for (int k = 31; k >= 0; --k) {          // walk own bins descending (regs)
            if (running + r[k] >= TOPK) { bstar_s = base + k; break; }
            running += r[k];
        }
    }
    // write start offsets (descending bin-major layout)
    {
        int run = cumAbove;
        #pragma unroll
        for (int k = 31; k >= 0; --k) { histL[base + k] = run; run += r[k]; }
    }
    __syncthreads();
    int Bstar = bstar_s;
    // counting-sort scatter: cursors turn start(b) into end(b); sentinel 0 < Bstar
    const uint32_t* b2 = (const uint32_t*)bin16;
    for (int t = tid; t < NFLAT / 2; t += 1024) {
        uint32_t v = b2[t];
        int b0 = (int)(v & 0xffffu), b1 = (int)(v >> 16);
        if (b0 >= Bstar) {
            int pos = atomicAdd(&histL[b0], 1);
            if (pos < CAP) candL[pos] = keys[2 * t];
        }
        if (b1 >= Bstar) {
            int pos = atomicAdd(&histL[b1], 1);
            if (pos < CAP) candL[pos] = keys[2 * t + 1];
        }
    }
    __syncthreads();
    int C = min(histL[Bstar], CAP);   // end(Bstar) == total candidate count
    // exact rank = segL (#cands in higher bins) + within-segment count
    for (int p = tid; p < C; p += 1024) {
        u64 k = candL[p];
        int b = (int)(k >> 49);
        int segL = (b == NBIN - 1) ? 0 : min(histL[b + 1], CAP);
        int segR = min(histL[b], CAP);
        int cnt = segL;
        for (int q = segL; q < segR; ++q)
            cnt += (candL[q] > k) ? 1 : 0;
        if (cnt < TOPK) {
            uint32_t o = (uint32_t)(k >> 32);
            uint32_t u = (o & 0x80000000u) ? (o ^ 0x80000000u) : ~o;  // inverse f2o
            top_val[cnt] = __uint_as_float(u);
            top_idx[cnt] = (int)(0xFFFFFFFFu - (uint32_t)(k & 0xFFFFFFFFu));
        }
    }
}

// --------------------------- per-block redundant prep + suppression matrix
__global__ void maskprep_kernel(const int* __restrict__ top_idx,
                                const float4* __restrict__ bbox,
                                u64* __restrict__ mask)
{
    __shared__ float4 sboxL[TOPK];   // 16000 B
    __shared__ float sareaL[TOPK];
    __shared__ int   labL[TOPK];
    __shared__ float redL[4];
    int tid = threadIdx.x;
    float m = -3.0e38f;
    for (int j = tid; j < TOPK; j += 256) {
        int idx = top_idx[j];
        int p = idx / NCLS;
        int lab = idx - p * NCLS;
        float4 b = bbox[p];
        sboxL[j] = b; labL[j] = lab;
        m = fmaxf(m, fmaxf(fmaxf(b.x, b.y), fmaxf(b.z, b.w)));
    }
    for (int o = 32; o > 0; o >>= 1) m = fmaxf(m, __shfl_down(m, o, 64));
    if ((tid & 63) == 0) redL[tid >> 6] = m;
    __syncthreads();
    float Mp1 = fmaxf(fmaxf(redL[0], redL[1]), fmaxf(redL[2], redL[3])) + 1.0f;
    for (int j = tid; j < TOPK; j += 256) {
        float off = (float)labL[j] * Mp1;
        float4 b = sboxL[j];
        float4 s = make_float4(b.x + off, b.y + off, b.z + off, b.w + off);
        sboxL[j] = s;
        sareaL[j] = fmaxf(s.z - s.x, 0.f) * fmaxf(s.w - s.y, 0.f);
    }
    __syncthreads();
    int g = blockIdx.x * 256 + tid;
    if (g < TOPK * NWORD) {
        int i = g >> 4, w = g & 15;
        float4 si = sboxL[i]; float ai = sareaL[i];
        int j0 = w * 64, j1 = min(j0 + 64, TOPK);
        u64 bits = 0;
        for (int j = max(j0, i + 1); j < j1; ++j) {
            float4 sj = sboxL[j];
            float ltx = fmaxf(si.x, sj.x), lty = fmaxf(si.y, sj.y);
            float rbx = fminf(si.z, sj.z), rby = fminf(si.w, sj.w);
            float iw = fmaxf(rbx - ltx, 0.f), ih = fmaxf(rby - lty, 0.f);
            float inter = iw * ih;
            float iou = inter / fmaxf(ai + sareaL[j] - inter, 1e-9f);
            if (iou > 0.6f) bits |= 1ull << (j - j0);
        }
        mask[g] = bits;
    }
}

// ---- greedy scan, sparsity-aware: only rows with outgoing edges processed.
__global__ void __launch_bounds__(1024, 4) scan_out_kernel(
    const u64* __restrict__ mask,
    const float* __restrict__ top_val, const int* __restrict__ top_idx,
    const float4* __restrict__ bbox, float* __restrict__ out)
{
    __shared__ uint32_t smask[1024 * 32];   // 131072 B; rows 1000..1023 zeroed
    __shared__ uint32_t skeep32[32];
    __shared__ uint32_t validw32[32];
    __shared__ uint32_t zmaskL[32];
    int tid = threadIdx.x;
    int lane64 = tid & 63, wv = tid >> 6;
    float tv = (tid < TOPK) ? top_val[tid] : -1.0f;
    u64 bal = __ballot(tid < TOPK && tv >= 0.05f);
    if (lane64 == 0) {
        validw32[wv * 2]     = (uint32_t)bal;
        validw32[wv * 2 + 1] = (uint32_t)(bal >> 32);
    }
    u64* smask64 = (u64*)smask;
    for (int g = tid; g < 1024 * NWORD; g += 1024)
        smask64[g] = (g < TOPK * NWORD) ? mask[g] : 0ull;
    __syncthreads();
    // per-row nonzero flags (rotated word order -> conflict-free)
    {
        uint32_t orv = 0;
        #pragma unroll
        for (int w = 0; w < 32; ++w) orv |= smask[tid * 32 + ((w + tid) & 31)];
        u64 zb = __ballot(orv != 0u);    // rows >=1000 are zero -> flag false
        if (lane64 == 0) {
            zmaskL[wv * 2]     = (uint32_t)zb;
            zmaskL[wv * 2 + 1] = (uint32_t)(zb >> 32);
        }
    }
    __syncthreads();
    if (tid < 32) {
        const int lane = tid;              // owns u32 word `lane` of the 1024-bit state
        uint32_t vwreg = validw32[lane];
        uint32_t zreg  = zmaskL[lane];
        uint32_t sup = 0;                  // suppressed bits, word `lane`
        for (int wc = 0; wc < 32; ++wc) {
            uint32_t nzw = (uint32_t)__builtin_amdgcn_readlane((int)zreg, wc);
            uint32_t avail = (uint32_t)__builtin_amdgcn_readlane((int)vwreg, wc)
                           & ~(uint32_t)__builtin_amdgcn_readlane((int)sup, wc);
            // 3-deep rotating prefetch over set bits (rows with outgoing edges)
            int p0 = -1, p1 = -1, p2 = -1;
            uint32_t R0 = 0, R1 = 0, R2 = 0;
            if (nzw) { p0 = __ffs(nzw) - 1; nzw &= nzw - 1;
                       R0 = smask[(wc * 32 + p0) * 32 + lane]; }
            if (nzw) { p1 = __ffs(nzw) - 1; nzw &= nzw - 1;
                       R1 = smask[(wc * 32 + p1) * 32 + lane]; }
            if (nzw) { p2 = __ffs(nzw) - 1; nzw &= nzw - 1;
                       R2 = smask[(wc * 32 + p2) * 32 + lane]; }
            while (p0 >= 0) {
                uint32_t rc = (uint32_t)__builtin_amdgcn_readlane((int)R0, wc);
                uint32_t kp = (avail >> p0) & 1u;
                uint32_t mm = 0u - kp;
                sup   |= R0 & mm;
                avail &= ~(rc & mm);
                p0 = p1; R0 = R1; p1 = p2; R1 = R2;
                if (nzw) { p2 = __ffs(nzw) - 1; nzw &= nzw - 1;
                           R2 = smask[(wc * 32 + p2) * 32 + lane]; }
                else p2 = -1;
            }
            if (lane == 0) skeep32[wc] = avail;   // frozen == final keep bits
        }
    }
    __syncthreads();
    int j = tid;
    if (j < TOPK) {
        int idx = top_idx[j];
        int p = idx / NCLS;
        int lab = idx - p * NCLS;
        float4 b = bbox[p];
        bool kp = (skeep32[j >> 5] >> (j & 31)) & 1u;
        float x1 = fminf(fmaxf(b.x, 0.f), 224.f);
        float y1 = fminf(fmaxf(b.y, 0.f), 398.f);
        float x2 = fminf(fmaxf(b.z, 0.f), 224.f);
        float y2 = fminf(fmaxf(b.w, 0.f), 398.f);
        kp = kp && ((x2 - x1) >= 1e-5f) && ((y2 - y1) >= 1e-5f);
        out[j * 4 + 0] = kp ? x1 : 0.f;
        out[j * 4 + 1] = kp ? y1 : 0.f;
        out[j * 4 + 2] = kp ? x2 : 0.f;
        out[j * 4 + 3] = kp ? y2 : 0.f;
        out[4 * TOPK + j] = kp ? tv : -1.0f;
        out[5 * TOPK + j] = (float)lab;
        out[6 * TOPK + j] = kp ? 1.0f : 0.0f;
    }
}

extern "C" void kernel_launch(void* const* d_in, const int* in_sizes, int n_in,
                              void* d_out, int out_size, void* d_ws, size_t ws_size,
                              hipStream_t stream)
{
    const float* s0 = (const float*)d_in[0];
    const float* l0 = (const float*)d_in[1];
    const float* c0 = (const float*)d_in[2];
    const float* s1 = (const float*)d_in[3];
    const float* l1 = (const float*)d_in[4];
    const float* c1 = (const float*)d_in[5];
    const float* s2 = (const float*)d_in[6];
    const float* l2 = (const float*)d_in[7];
    const float* c2 = (const float*)d_in[8];

    uint8_t* ws = (uint8_t*)d_ws;
    u64*    keys = (u64*)   (ws);              // 37520*8  = 300160 B
    float4* bbox = (float4*)(ws + 300160);     // 469*16   =   7504 B
    int*    hist = (int*)   (ws + 307664);     // 32768*4  = 131072 B (dead after topk)
    u64*    mask = (u64*)   (ws + 307664);     // aliases hist: 16000*8 = 128000 B
    float*  tval = (float*) (ws + 438736);     // 1000*4
    int*    tidx = (int*)   (ws + 442736);     // 1000*4
    unsigned short* bin16 = (unsigned short*)(ws + 446736);  // 75040 -> 521776 B total

    zero_hist_kernel<<<dim3(32), 256, 0, stream>>>(hist);
    decode_kernel<<<dim3((NFLAT + 255) / 256), 256, 0, stream>>>(
        s0, l0, c0, s1, l1, c1, s2, l2, c2, keys, bbox, bin16, hist);
    topk_kernel<<<1, 1024, 0, stream>>>(keys, bin16, hist, tval, tidx);
    maskprep_kernel<<<dim3((TOPK * NWORD + 255) / 256), 256, 0, stream>>>(tidx, bbox, mask);
    scan_out_kernel<<<1, 1024, 0, stream>>>(mask, tval, tidx, bbox, (float*)d_out);
}

// Round 12
// 79.022 us; speedup vs baseline: 1.3003x; 1.2960x over previous
//
#include <hip/hip_runtime.h>
#include <stdint.h>

#define NLOC 469
#define NCLS 80
#define NFLAT 37520
#define TOPK 1000
#define NBIN 32768       // 15-bit histogram over key top bits
#define CAP 2048         // candidate capacity (LDS)

typedef unsigned long long u64;

__device__ __forceinline__ float sigm(float x) { return 1.0f / (1.0f + expf(-x)); }

// order-preserving float -> uint32 (greater float => greater uint)
__device__ __forceinline__ uint32_t f2o(float f) {
    uint32_t u = __float_as_uint(f);
    return (u & 0x80000000u) ? ~u : (u | 0x80000000u);
}

// ------------------------------------------- K1: decode (parallel, 147 blocks)
__global__ void decode_kernel(
    const float* __restrict__ s0, const float* __restrict__ l0, const float* __restrict__ c0,
    const float* __restrict__ s1, const float* __restrict__ l1, const float* __restrict__ c1,
    const float* __restrict__ s2, const float* __restrict__ l2, const float* __restrict__ c2,
    u64* __restrict__ keys, float4* __restrict__ bbox, unsigned short* __restrict__ bin16)
{
    int t = blockIdx.x * blockDim.x + threadIdx.x;
    if (t < NFLAT) {
        int p = t / NCLS;
        int k = t - p * NCLS;
        int c = k + 1;                       // class channel (0 = background, dropped)
        const float* sr; const float* cr; int local, hw;
        if (p < 350)      { sr = s0; cr = c0; local = p;       hw = 350; }
        else if (p < 441) { sr = s1; cr = c1; local = p - 350; hw = 91;  }
        else              { sr = s2; cr = c2; local = p - 441; hw = 28;  }
        float val = sqrtf(sigm(sr[c * hw + local]) * sigm(cr[local]));
        bool valid = (val >= 0.05f);
        float masked = valid ? val : -1.0f;
        // key: value-major, tie -> lower index wins (larger low word)
        u64 key = ((u64)f2o(masked) << 32) | (u64)(0xFFFFFFFFu - (uint32_t)t);
        keys[t] = key;
        // valid bins >= f2o(0.05)>>17 = 24230 >> 0; sentinel 0 marks invalid
        bin16[t] = valid ? (unsigned short)(key >> 49) : (unsigned short)0;
    }
    if (t < NLOC) {
        int p = t;
        const float* lr; int local, hw, w; float is;
        if (p < 350)      { lr = l0; local = p;       hw = 350; w = 25; is = 16.0f; }
        else if (p < 441) { lr = l1; local = p - 350; hw = 91;  w = 13; is = 32.0f; }
        else              { lr = l2; local = p - 441; hw = 28;  w = 7;  is = 64.0f; }
        int y = local / w, x = local - y * w;
        float px = ((float)x + 0.5f) * is;
        float py = ((float)y + 0.5f) * is;
        float L = lr[local] * is;
        float T = lr[hw + local] * is;
        float R = lr[2 * hw + local] * is;
        float B = lr[3 * hw + local] * is;
        bbox[p] = make_float4(px - L, py - T, px + R, py + B);
    }
}

// ---------- K2: fused topk + class-sparse mask + greedy scan + output (1 block)
__global__ void __launch_bounds__(1024, 4) fused_kernel(
    const u64* __restrict__ keys, const unsigned short* __restrict__ bin16,
    const float4* __restrict__ bbox, float* __restrict__ out)
{
    // phase A: histL[32768](128K) + candL[2048](16K)      = 147456 B
    // phase C: smask[32768 u32](128K) + sbox[1000]f4(16000) + lab8(1000)
    //          + csorted u16(2000) + cls arrays              ~ 150768 B
    __shared__ __align__(16) unsigned char ubuf[150784];
    int*      histL   = (int*)ubuf;
    u64*      candL   = (u64*)(ubuf + 131072);
    uint32_t* smask   = (uint32_t*)ubuf;
    float4*   sboxL   = (float4*)(ubuf + 131072);
    unsigned char* lab8 = (unsigned char*)(ubuf + 147072);
    unsigned short* csorted = (unsigned short*)(ubuf + 148072);
    int*      clsStart = (int*)(ubuf + 150080);   // 80 ints
    int*      clsCur   = (int*)(ubuf + 150400);   // 80 ints (cnt -> cursor -> end)

    __shared__ float tvalL[TOPK];
    __shared__ int   tidxL[TOPK];
    __shared__ uint32_t skeep32[32], validw32[32], zmaskL[32];
    __shared__ int wsum[16];
    __shared__ int bstar_s;
    __shared__ float redMax[16], redMin[16];
    __shared__ float Mp1_s;
    __shared__ int dmax_s;

    int tid = threadIdx.x;
    int lane = tid & 63, wv = tid >> 6;

    // ---- A1: zero hist
    for (int z = tid; z < NBIN; z += 1024) histL[z] = 0;
    __syncthreads();
    // ---- A2: build hist from packed bins (valid-only; sentinel 0 skipped)
    const uint32_t* b2 = (const uint32_t*)bin16;
    for (int t = tid; t < NFLAT / 2; t += 1024) {
        uint32_t v = b2[t];
        int b0 = (int)(v & 0xffffu), b1 = (int)(v >> 16);
        if (b0) atomicAdd(&histL[b0], 1);
        if (b1) atomicAdd(&histL[b1], 1);
    }
    __syncthreads();
    // ---- A3: select cutoff bin Bstar (thread tid owns bins [base, base+32))
    int base = NBIN - 32 * (tid + 1);
    int r[32];
    int gsum = 0;
    #pragma unroll
    for (int k = 0; k < 32; ++k) { r[k] = histL[base + k]; gsum += r[k]; }
    int ws = gsum;
    #pragma unroll
    for (int d = 1; d < 64; d <<= 1) {
        int v = __shfl_up(ws, d, 64);
        if (lane >= d) ws += v;
    }
    if (lane == 63) wsum[wv] = ws;
    __syncthreads();
    if (tid < 16) {
        int v = wsum[tid];
        int sc = v;
        #pragma unroll
        for (int d = 1; d < 16; d <<= 1) {
            int u2 = __shfl_up(sc, d, 64);
            if (tid >= d) sc += u2;
        }
        wsum[tid] = sc - v;                  // exclusive wave prefix
    }
    __syncthreads();
    int incl = ws + wsum[wv];
    int cumAbove = incl - gsum;
    if (cumAbove < TOPK && incl >= TOPK) {
        int running = cumAbove;
        #pragma unroll
        for (int k = 31; k >= 0; --k) {
            if (running + r[k] >= TOPK) { bstar_s = base + k; break; }
            running += r[k];
        }
    }
    {   // start offsets (descending bin-major)
        int run = cumAbove;
        #pragma unroll
        for (int k = 31; k >= 0; --k) { histL[base + k] = run; run += r[k]; }
    }
    __syncthreads();
    int Bstar = bstar_s;
    // ---- A4: counting-sort scatter of candidates
    for (int t = tid; t < NFLAT / 2; t += 1024) {
        uint32_t v = b2[t];
        int b0 = (int)(v & 0xffffu), b1 = (int)(v >> 16);
        if (b0 >= Bstar) {
            int pos = atomicAdd(&histL[b0], 1);
            if (pos < CAP) candL[pos] = keys[2 * t];
        }
        if (b1 >= Bstar) {
            int pos = atomicAdd(&histL[b1], 1);
            if (pos < CAP) candL[pos] = keys[2 * t + 1];
        }
    }
    __syncthreads();
    int C = min(histL[Bstar], CAP);
    // ---- A5: exact rank within bin segment -> tval/tidx (LDS)
    for (int p = tid; p < C; p += 1024) {
        u64 k = candL[p];
        int b = (int)(k >> 49);
        int segL = (b == NBIN - 1) ? 0 : min(histL[b + 1], CAP);
        int segR = min(histL[b], CAP);
        int cnt = segL;
        for (int q = segL; q < segR; ++q)
            cnt += (candL[q] > k) ? 1 : 0;
        if (cnt < TOPK) {
            uint32_t o = (uint32_t)(k >> 32);
            uint32_t u = (o & 0x80000000u) ? (o ^ 0x80000000u) : ~o;  // inverse f2o
            tvalL[cnt] = __uint_as_float(u);
            tidxL[cnt] = (int)(0xFFFFFFFFu - (uint32_t)(k & 0xFFFFFFFFu));
        }
    }
    __syncthreads();

    // ---- C1a: zero smask (reuses histL bytes); gather raw boxes; max/min reduce
    for (int z = tid; z < 1024 * 32; z += 1024) smask[z] = 0u;
    float m = -3.0e38f, lmin = 3.0e38f;
    if (tid < TOPK) {
        int idx = tidxL[tid];
        int p = idx / NCLS;
        int lab = idx - p * NCLS;
        float4 b = bbox[p];
        sboxL[tid] = b;                      // raw for now
        lab8[tid] = (unsigned char)lab;
        m = fmaxf(fmaxf(b.x, b.y), fmaxf(b.z, b.w));
        lmin = fminf(b.x, b.y);
    }
    for (int o = 32; o > 0; o >>= 1) {
        m = fmaxf(m, __shfl_down(m, o, 64));
        lmin = fminf(lmin, __shfl_down(lmin, o, 64));
    }
    if (lane == 0) { redMax[wv] = m; redMin[wv] = lmin; }
    __syncthreads();
    if (tid == 0) {
        float mm = redMax[0], ll = redMin[0];
        for (int q = 1; q < 16; ++q) { mm = fmaxf(mm, redMax[q]); ll = fminf(ll, redMin[q]); }
        float Mp1 = mm + 1.0f;
        Mp1_s = Mp1;
        int dm = 79;
        if (Mp1 > 0.0f) {
            float ratio = (mm - ll) / Mp1;
            dm = (int)ceilf(ratio);
            if (dm < 0) dm = 0;
            if (dm > 79) dm = 79;
        }
        dmax_s = dm;
    }
    __syncthreads();
    // ---- C1b: apply class offset in place (exactly as reference)
    float Mp1 = Mp1_s;
    if (tid < TOPK) {
        float off = (float)lab8[tid] * Mp1;
        float4 b = sboxL[tid];
        sboxL[tid] = make_float4(b.x + off, b.y + off, b.z + off, b.w + off);
    }
    // ---- C2: group rows by class (counting sort)
    if (tid < NCLS) clsCur[tid] = 0;
    __syncthreads();
    if (tid < TOPK) atomicAdd(&clsCur[lab8[tid]], 1);
    __syncthreads();
    if (tid < NCLS) clsStart[tid] = clsCur[tid];
    __syncthreads();
    for (int d = 1; d < NCLS; d <<= 1) {     // Hillis-Steele inclusive scan
        int v = (tid < NCLS && tid >= d) ? clsStart[tid - d] : 0;
        __syncthreads();
        if (tid < NCLS) clsStart[tid] += v;
        __syncthreads();
    }
    if (tid < NCLS) {
        int s = clsStart[tid] - clsCur[tid]; // exclusive
        clsStart[tid] = s;
        clsCur[tid] = s;                     // becomes cursor
    }
    __syncthreads();
    if (tid < TOPK) {
        int pos = atomicAdd(&clsCur[lab8[tid]], 1);
        csorted[pos] = (unsigned short)tid;
    }
    __syncthreads();                         // clsCur[c] is now END of class c
    // ---- C3: sparse pair IoU -> mask bits (row tid owned exclusively)
    bool nz = false;
    if (tid < TOPK) {
        int i = tid, c = lab8[i];
        float4 si = sboxL[i];
        float ai = fmaxf(si.z - si.x, 0.f) * fmaxf(si.w - si.y, 0.f);
        int dmax = dmax_s;
        int clo = c - dmax; if (clo < 0) clo = 0;
        int chi = c + dmax; if (chi > NCLS - 1) chi = NCLS - 1;
        for (int cc = clo; cc <= chi; ++cc) {
            int mE = clsCur[cc];
            for (int mm2 = clsStart[cc]; mm2 < mE; ++mm2) {
                int j = csorted[mm2];
                if (j > i) {
                    float4 sj = sboxL[j];
                    float aj = fmaxf(sj.z - sj.x, 0.f) * fmaxf(sj.w - sj.y, 0.f);
                    float ltx = fmaxf(si.x, sj.x), lty = fmaxf(si.y, sj.y);
                    float rbx = fminf(si.z, sj.z), rby = fminf(si.w, sj.w);
                    float iw = fmaxf(rbx - ltx, 0.f), ih = fmaxf(rby - lty, 0.f);
                    float inter = iw * ih;
                    float iou = inter / fmaxf(ai + aj - inter, 1e-9f);
                    if (iou > 0.6f) {
                        smask[i * 32 + (j >> 5)] |= 1u << (j & 31);
                        nz = true;
                    }
                }
            }
        }
    }
    // zmask + validw ballots (all lanes participate)
    {
        u64 zb = __ballot(nz);
        if (lane == 0) {
            zmaskL[wv * 2]     = (uint32_t)zb;
            zmaskL[wv * 2 + 1] = (uint32_t)(zb >> 32);
        }
        float tv = (tid < TOPK) ? tvalL[tid] : -1.0f;
        u64 bal = __ballot(tid < TOPK && tv >= 0.05f);
        if (lane == 0) {
            validw32[wv * 2]     = (uint32_t)bal;
            validw32[wv * 2 + 1] = (uint32_t)(bal >> 32);
        }
    }
    __syncthreads();
    // ---- C4: sparse greedy scan (single wave, r11-proven)
    if (tid < 32) {
        const int ln = tid;
        uint32_t vwreg = validw32[ln];
        uint32_t zreg  = zmaskL[ln];
        uint32_t sup = 0;
        for (int wc = 0; wc < 32; ++wc) {
            uint32_t nzw = (uint32_t)__builtin_amdgcn_readlane((int)zreg, wc);
            uint32_t avail = (uint32_t)__builtin_amdgcn_readlane((int)vwreg, wc)
                           & ~(uint32_t)__builtin_amdgcn_readlane((int)sup, wc);
            int p0 = -1, p1 = -1, p2 = -1;
            uint32_t R0 = 0, R1 = 0, R2 = 0;
            if (nzw) { p0 = __ffs(nzw) - 1; nzw &= nzw - 1;
                       R0 = smask[(wc * 32 + p0) * 32 + ln]; }
            if (nzw) { p1 = __ffs(nzw) - 1; nzw &= nzw - 1;
                       R1 = smask[(wc * 32 + p1) * 32 + ln]; }
            if (nzw) { p2 = __ffs(nzw) - 1; nzw &= nzw - 1;
                       R2 = smask[(wc * 32 + p2) * 32 + ln]; }
            while (p0 >= 0) {
                uint32_t rc = (uint32_t)__builtin_amdgcn_readlane((int)R0, wc);
                uint32_t kp = (avail >> p0) & 1u;
                uint32_t mm = 0u - kp;
                sup   |= R0 & mm;
                avail &= ~(rc & mm);
                p0 = p1; R0 = R1; p1 = p2; R1 = R2;
                if (nzw) { p2 = __ffs(nzw) - 1; nzw &= nzw - 1;
                           R2 = smask[(wc * 32 + p2) * 32 + ln]; }
                else p2 = -1;
            }
            if (ln == 0) skeep32[wc] = avail;   // frozen == final keep bits
        }
    }
    __syncthreads();
    // ---- C5: clip + output
    if (tid < TOPK) {
        int idx = tidxL[tid];
        int p = idx / NCLS;
        int lab = idx - p * NCLS;
        float4 b = bbox[p];                  // raw box (re-gather)
        float tv = tvalL[tid];
        bool kp = (skeep32[tid >> 5] >> (tid & 31)) & 1u;
        float x1 = fminf(fmaxf(b.x, 0.f), 224.f);
        float y1 = fminf(fmaxf(b.y, 0.f), 398.f);
        float x2 = fminf(fmaxf(b.z, 0.f), 224.f);
        float y2 = fminf(fmaxf(b.w, 0.f), 398.f);
        kp = kp && ((x2 - x1) >= 1e-5f) && ((y2 - y1) >= 1e-5f);
        out[tid * 4 + 0] = kp ? x1 : 0.f;
        out[tid * 4 + 1] = kp ? y1 : 0.f;
        out[tid * 4 + 2] = kp ? x2 : 0.f;
        out[tid * 4 + 3] = kp ? y2 : 0.f;
        out[4 * TOPK + tid] = kp ? tv : -1.0f;
        out[5 * TOPK + tid] = (float)lab;
        out[6 * TOPK + tid] = kp ? 1.0f : 0.0f;
    }
}

extern "C" void kernel_launch(void* const* d_in, const int* in_sizes, int n_in,
                              void* d_out, int out_size, void* d_ws, size_t ws_size,
                              hipStream_t stream)
{
    const float* s0 = (const float*)d_in[0];
    const float* l0 = (const float*)d_in[1];
    const float* c0 = (const float*)d_in[2];
    const float* s1 = (const float*)d_in[3];
    const float* l1 = (const float*)d_in[4];
    const float* c1 = (const float*)d_in[5];
    const float* s2 = (const float*)d_in[6];
    const float* l2 = (const float*)d_in[7];
    const float* c2 = (const float*)d_in[8];

    uint8_t* ws = (uint8_t*)d_ws;
    u64*    keys = (u64*)   (ws);              // 37520*8  = 300160 B
    float4* bbox = (float4*)(ws + 300160);     // 469*16   =   7504 B
    unsigned short* bin16 = (unsigned short*)(ws + 307664);  // 75040 -> 382704 B total

    decode_kernel<<<dim3((NFLAT + 255) / 256), 256, 0, stream>>>(
        s0, l0, c0, s1, l1, c1, s2, l2, c2, keys, bbox, bin16);
    fused_kernel<<<1, 1024, 0, stream>>>(keys, bin16, bbox, (float*)d_out);
}

// Round 13
// 67.653 us; speedup vs baseline: 1.5189x; 1.1680x over previous
//
#include <hip/hip_runtime.h>
#include <stdint.h>

#define NLOC 469
#define NCLS 80
#define NFLAT 37520
#define TOPK 1000
#define NB 512           // compact hist: valid bin15 in [24230,24511] subset of [BOFF,BOFF+511]
#define BOFF 24192
#define CAP 2048         // candidate capacity (LDS)

typedef unsigned long long u64;

__device__ __forceinline__ float sigm(float x) { return 1.0f / (1.0f + expf(-x)); }

// order-preserving float -> uint32 (greater float => greater uint)
__device__ __forceinline__ uint32_t f2o(float f) {
    uint32_t u = __float_as_uint(f);
    return (u & 0x80000000u) ? ~u : (u | 0x80000000u);
}

// ------------------------------------------- K1: decode (parallel, 147 blocks)
__global__ void decode_kernel(
    const float* __restrict__ s0, const float* __restrict__ l0, const float* __restrict__ c0,
    const float* __restrict__ s1, const float* __restrict__ l1, const float* __restrict__ c1,
    const float* __restrict__ s2, const float* __restrict__ l2, const float* __restrict__ c2,
    u64* __restrict__ keys, float4* __restrict__ bbox, unsigned short* __restrict__ bin16)
{
    int t = blockIdx.x * blockDim.x + threadIdx.x;
    if (t < NFLAT) {
        int p = t / NCLS;
        int k = t - p * NCLS;
        int c = k + 1;                       // class channel (0 = background, dropped)
        const float* sr; const float* cr; int local, hw;
        if (p < 350)      { sr = s0; cr = c0; local = p;       hw = 350; }
        else if (p < 441) { sr = s1; cr = c1; local = p - 350; hw = 91;  }
        else              { sr = s2; cr = c2; local = p - 441; hw = 28;  }
        float val = sqrtf(sigm(sr[c * hw + local]) * sigm(cr[local]));
        bool valid = (val >= 0.05f);
        float masked = valid ? val : -1.0f;
        // key: value-major, tie -> lower index wins (larger low word)
        u64 key = ((u64)f2o(masked) << 32) | (u64)(0xFFFFFFFFu - (uint32_t)t);
        keys[t] = key;
        // valid bin15 in [24230, 24511]; sentinel 0 marks invalid
        bin16[t] = valid ? (unsigned short)(key >> 49) : (unsigned short)0;
    }
    if (t < NLOC) {
        int p = t;
        const float* lr; int local, hw, w; float is;
        if (p < 350)      { lr = l0; local = p;       hw = 350; w = 25; is = 16.0f; }
        else if (p < 441) { lr = l1; local = p - 350; hw = 91;  w = 13; is = 32.0f; }
        else              { lr = l2; local = p - 441; hw = 28;  w = 7;  is = 64.0f; }
        int y = local / w, x = local - y * w;
        float px = ((float)x + 0.5f) * is;
        float py = ((float)y + 0.5f) * is;
        float L = lr[local] * is;
        float T = lr[hw + local] * is;
        float R = lr[2 * hw + local] * is;
        float B = lr[3 * hw + local] * is;
        bbox[p] = make_float4(px - L, py - T, px + R, py + B);
    }
}

// ---------- K2: fused topk + class-sparse mask + greedy scan + output (1 block)
__global__ void __launch_bounds__(1024, 4) fused_kernel(
    const u64* __restrict__ keys, const unsigned short* __restrict__ bin16,
    const float4* __restrict__ bbox, float* __restrict__ out)
{
    // phase A: histS[512](2K) + candL[2048](16K) live in ubuf's first 18.5K
    // phase C: smask[32768 u32](128K) overlays ubuf entirely
    __shared__ __align__(16) unsigned char ubuf[131072];
    int*      histS = (int*)ubuf;                   // 512 ints
    u64*      candL = (u64*)(ubuf + 2048);          // 2048 u64
    uint32_t* smask = (uint32_t*)ubuf;              // 32768 u32 (phase C)

    __shared__ float4 sboxL[TOPK];                  // 16000 B
    __shared__ unsigned char lab8[TOPK];
    __shared__ unsigned short csorted[TOPK];
    __shared__ int clsStart[NCLS], clsCur[NCLS];
    __shared__ float tvalL[TOPK];
    __shared__ int   tidxL[TOPK];
    __shared__ uint32_t skeep32[32], validw32[32], zmaskL[32];
    __shared__ int bstar_s;
    __shared__ float redMax[16], redMin[16];
    __shared__ float Mp1_s;
    __shared__ int dmax_s;

    int tid = threadIdx.x;
    int lane = tid & 63, wv = tid >> 6;

    // ---- A0: register-batch prefetch of packed bins (issued before barrier;
    //          independent of LDS, so loads fly during hist zeroing)
    const uint32_t* b2 = (const uint32_t*)bin16;    // 2 bins per u32, NFLAT/2 = 18760
    const int nw = (tid < 328) ? 19 : 18;           // 18760 = 18*1024 + 328
    uint32_t vbuf[19];
    #pragma unroll
    for (int k = 0; k < 19; ++k) {
        int t = tid + (k << 10);
        if (t < NFLAT / 2) vbuf[k] = b2[t];
    }
    if (tid == 0) bstar_s = 0;
    if (tid < NB) histS[tid] = 0;
    __syncthreads();
    // ---- A2: hist build from registers (valid-only; sentinel 0 skipped)
    #pragma unroll
    for (int k = 0; k < 19; ++k) {
        if (k < nw) {
            uint32_t v = vbuf[k];
            int b0 = (int)(v & 0xffffu), b1 = (int)(v >> 16);
            if (b0) atomicAdd(&histS[b0 - BOFF], 1);
            if (b1) atomicAdd(&histS[b1 - BOFF], 1);
        }
    }
    __syncthreads();
    // ---- A3: single-wave select over 512 bins; others init tval/tidx
    if (tid < 64) {
        int bs = NB - 8 * (tid + 1);                // lane 0 owns HIGHEST 8 bins
        int h[8];
        int s = 0;
        #pragma unroll
        for (int k = 0; k < 8; ++k) { h[k] = histS[bs + k]; s += h[k]; }
        int ws = s;
        #pragma unroll
        for (int d = 1; d < 64; d <<= 1) {
            int v = __shfl_up(ws, d, 64);
            if (tid >= d) ws += v;
        }
        int cumAbove = ws - s;
        if (cumAbove < TOPK && ws >= TOPK) {        // exactly one lane crosses
            int running = cumAbove;
            #pragma unroll
            for (int k = 7; k >= 0; --k) {
                if (running + h[k] >= TOPK) { bstar_s = BOFF + bs + k; break; }
                running += h[k];
            }
        }
        int run = cumAbove;                         // starts, descending bin-major
        #pragma unroll
        for (int k = 7; k >= 0; --k) { histS[bs + k] = run; run += h[k]; }
    }
    if (tid < TOPK) { tvalL[tid] = -1.0f; tidxL[tid] = 0; }
    __syncthreads();
    int Bstar = bstar_s;
    // ---- A4: counting-sort scatter (register reuse -> no second bin read)
    #pragma unroll
    for (int k = 0; k < 19; ++k) {
        if (k < nw) {
            uint32_t v = vbuf[k];
            int b0 = (int)(v & 0xffffu), b1 = (int)(v >> 16);
            int t2 = (tid + (k << 10)) * 2;
            if (b0 >= Bstar) {
                int pos = atomicAdd(&histS[b0 - BOFF], 1);
                if (pos < CAP) candL[pos] = keys[t2];
            }
            if (b1 >= Bstar) {
                int pos = atomicAdd(&histS[b1 - BOFF], 1);
                if (pos < CAP) candL[pos] = keys[t2 + 1];
            }
        }
    }
    __syncthreads();
    int C = min(histS[Bstar - BOFF], CAP);          // end(Bstar) == candidate count
    // ---- A5: exact rank within bin segment -> tval/tidx (LDS)
    for (int p = tid; p < C; p += 1024) {
        u64 k = candL[p];
        int bidx = (int)(k >> 49) - BOFF;
        int segL = (bidx == NB - 1) ? 0 : min(histS[bidx + 1], CAP);
        int segR = min(histS[bidx], CAP);
        int cnt = segL;
        for (int q = segL; q < segR; ++q)
            cnt += (candL[q] > k) ? 1 : 0;
        if (cnt < TOPK) {
            uint32_t o = (uint32_t)(k >> 32);
            uint32_t u = (o & 0x80000000u) ? (o ^ 0x80000000u) : ~o;  // inverse f2o
            tvalL[cnt] = __uint_as_float(u);
            tidxL[cnt] = (int)(0xFFFFFFFFu - (uint32_t)(k & 0xFFFFFFFFu));
        }
    }
    __syncthreads();

    // ---- C1a: zero smask rows 0..999; gather raw boxes; max/min reduce
    for (int z = tid; z < TOPK * 32; z += 1024) smask[z] = 0u;
    float m = -3.0e38f, lmin = 3.0e38f;
    if (tid < TOPK) {
        int idx = tidxL[tid];
        int p = idx / NCLS;
        int lab = idx - p * NCLS;
        float4 b = bbox[p];
        sboxL[tid] = b;                      // raw for now
        lab8[tid] = (unsigned char)lab;
        m = fmaxf(fmaxf(b.x, b.y), fmaxf(b.z, b.w));
        lmin = fminf(b.x, b.y);
    }
    for (int o = 32; o > 0; o >>= 1) {
        m = fmaxf(m, __shfl_down(m, o, 64));
        lmin = fminf(lmin, __shfl_down(lmin, o, 64));
    }
    if (lane == 0) { redMax[wv] = m; redMin[wv] = lmin; }
    __syncthreads();
    if (tid == 0) {
        float mm = redMax[0], ll = redMin[0];
        for (int q = 1; q < 16; ++q) { mm = fmaxf(mm, redMax[q]); ll = fminf(ll, redMin[q]); }
        float Mp1 = mm + 1.0f;
        Mp1_s = Mp1;
        int dm = 79;
        if (Mp1 > 0.0f) {
            float ratio = (mm - ll) / Mp1;
            dm = (int)ceilf(ratio);
            if (dm < 0) dm = 0;
            if (dm > 79) dm = 79;
        }
        dmax_s = dm;
    }
    __syncthreads();
    // ---- C1b: apply class offset in place (exactly as reference)
    float Mp1 = Mp1_s;
    if (tid < TOPK) {
        float off = (float)lab8[tid] * Mp1;
        float4 b = sboxL[tid];
        sboxL[tid] = make_float4(b.x + off, b.y + off, b.z + off, b.w + off);
    }
    // ---- C2: group rows by class (counting sort)
    if (tid < NCLS) clsCur[tid] = 0;
    __syncthreads();
    if (tid < TOPK) atomicAdd(&clsCur[lab8[tid]], 1);
    __syncthreads();
    if (tid < NCLS) clsStart[tid] = clsCur[tid];
    __syncthreads();
    for (int d = 1; d < NCLS; d <<= 1) {     // Hillis-Steele inclusive scan
        int v = (tid < NCLS && tid >= d) ? clsStart[tid - d] : 0;
        __syncthreads();
        if (tid < NCLS) clsStart[tid] += v;
        __syncthreads();
    }
    if (tid < NCLS) {
        int s = clsStart[tid] - clsCur[tid]; // exclusive
        clsStart[tid] = s;
        clsCur[tid] = s;                     // becomes cursor
    }
    __syncthreads();
    if (tid < TOPK) {
        int pos = atomicAdd(&clsCur[lab8[tid]], 1);
        csorted[pos] = (unsigned short)tid;
    }
    __syncthreads();                         // clsCur[c] is now END of class c
    // ---- C3: sparse pair IoU -> mask bits (row tid owned exclusively)
    bool nz = false;
    if (tid < TOPK) {
        int i = tid, c = lab8[i];
        float4 si = sboxL[i];
        float ai = fmaxf(si.z - si.x, 0.f) * fmaxf(si.w - si.y, 0.f);
        int dmax = dmax_s;
        int clo = c - dmax; if (clo < 0) clo = 0;
        int chi = c + dmax; if (chi > NCLS - 1) chi = NCLS - 1;
        for (int cc = clo; cc <= chi; ++cc) {
            int mE = clsCur[cc];
            for (int mm2 = clsStart[cc]; mm2 < mE; ++mm2) {
                int j = csorted[mm2];
                if (j > i) {
                    float4 sj = sboxL[j];
                    float aj = fmaxf(sj.z - sj.x, 0.f) * fmaxf(sj.w - sj.y, 0.f);
                    float ltx = fmaxf(si.x, sj.x), lty = fmaxf(si.y, sj.y);
                    float rbx = fminf(si.z, sj.z), rby = fminf(si.w, sj.w);
                    float iw = fmaxf(rbx - ltx, 0.f), ih = fmaxf(rby - lty, 0.f);
                    float inter = iw * ih;
                    float iou = inter / fmaxf(ai + aj - inter, 1e-9f);
                    if (iou > 0.6f) {
                        smask[i * 32 + (j >> 5)] |= 1u << (j & 31);
                        nz = true;
                    }
                }
            }
        }
    }
    // zmask + validw ballots (all lanes participate)
    {
        u64 zb = __ballot(nz);
        if (lane == 0) {
            zmaskL[wv * 2]     = (uint32_t)zb;
            zmaskL[wv * 2 + 1] = (uint32_t)(zb >> 32);
        }
        float tv = (tid < TOPK) ? tvalL[tid] : -1.0f;
        u64 bal = __ballot(tid < TOPK && tv >= 0.05f);
        if (lane == 0) {
            validw32[wv * 2]     = (uint32_t)bal;
            validw32[wv * 2 + 1] = (uint32_t)(bal >> 32);
        }
    }
    __syncthreads();
    // ---- C4: sparse greedy scan (single wave)
    if (tid < 32) {
        const int ln = tid;
        uint32_t vwreg = validw32[ln];
        uint32_t zreg  = zmaskL[ln];
        uint32_t sup = 0;
        for (int wc = 0; wc < 32; ++wc) {
            uint32_t nzw = (uint32_t)__builtin_amdgcn_readlane((int)zreg, wc);
            uint32_t avail = (uint32_t)__builtin_amdgcn_readlane((int)vwreg, wc)
                           & ~(uint32_t)__builtin_amdgcn_readlane((int)sup, wc);
            int p0 = -1, p1 = -1, p2 = -1;
            uint32_t R0 = 0, R1 = 0, R2 = 0;
            if (nzw) { p0 = __ffs(nzw) - 1; nzw &= nzw - 1;
                       R0 = smask[(wc * 32 + p0) * 32 + ln]; }
            if (nzw) { p1 = __ffs(nzw) - 1; nzw &= nzw - 1;
                       R1 = smask[(wc * 32 + p1) * 32 + ln]; }
            if (nzw) { p2 = __ffs(nzw) - 1; nzw &= nzw - 1;
                       R2 = smask[(wc * 32 + p2) * 32 + ln]; }
            while (p0 >= 0) {
                uint32_t rc = (uint32_t)__builtin_amdgcn_readlane((int)R0, wc);
                uint32_t kp = (avail >> p0) & 1u;
                uint32_t mm = 0u - kp;
                sup   |= R0 & mm;
                avail &= ~(rc & mm);
                p0 = p1; R0 = R1; p1 = p2; R1 = R2;
                if (nzw) { p2 = __ffs(nzw) - 1; nzw &= nzw - 1;
                           R2 = smask[(wc * 32 + p2) * 32 + ln]; }
                else p2 = -1;
            }
            if (ln == 0) skeep32[wc] = avail;   // frozen == final keep bits
        }
    }
    __syncthreads();
    // ---- C5: clip + output
    if (tid < TOPK) {
        int idx = tidxL[tid];
        int p = idx / NCLS;
        int lab = idx - p * NCLS;
        float4 b = bbox[p];                  // raw box (re-gather)
        float tv = tvalL[tid];
        bool kp = (skeep32[tid >> 5] >> (tid & 31)) & 1u;
        float x1 = fminf(fmaxf(b.x, 0.f), 224.f);
        float y1 = fminf(fmaxf(b.y, 0.f), 398.f);
        float x2 = fminf(fmaxf(b.z, 0.f), 224.f);
        float y2 = fminf(fmaxf(b.w, 0.f), 398.f);
        kp = kp && ((x2 - x1) >= 1e-5f) && ((y2 - y1) >= 1e-5f);
        out[tid * 4 + 0] = kp ? x1 : 0.f;
        out[tid * 4 + 1] = kp ? y1 : 0.f;
        out[tid * 4 + 2] = kp ? x2 : 0.f;
        out[tid * 4 + 3] = kp ? y2 : 0.f;
        out[4 * TOPK + tid] = kp ? tv : -1.0f;
        out[5 * TOPK + tid] = (float)lab;
        out[6 * TOPK + tid] = kp ? 1.0f : 0.0f;
    }
}

extern "C" void kernel_launch(void* const* d_in, const int* in_sizes, int n_in,
                              void* d_out, int out_size, void* d_ws, size_t ws_size,
                              hipStream_t stream)
{
    const float* s0 = (const float*)d_in[0];
    const float* l0 = (const float*)d_in[1];
    const float* c0 = (const float*)d_in[2];
    const float* s1 = (const float*)d_in[3];
    const float* l1 = (const float*)d_in[4];
    const float* c1 = (const float*)d_in[5];
    const float* s2 = (const float*)d_in[6];
    const float* l2 = (const float*)d_in[7];
    const float* c2 = (const float*)d_in[8];

    uint8_t* ws = (uint8_t*)d_ws;
    u64*    keys = (u64*)   (ws);              // 37520*8  = 300160 B
    float4* bbox = (float4*)(ws + 300160);     // 469*16   =   7504 B
    unsigned short* bin16 = (unsigned short*)(ws + 307664);  // 75040 -> 382704 B total

    decode_kernel<<<dim3((NFLAT + 255) / 256), 256, 0, stream>>>(
        s0, l0, c0, s1, l1, c1, s2, l2, c2, keys, bbox, bin16);
    fused_kernel<<<1, 1024, 0, stream>>>(keys, bin16, bbox, (float*)d_out);
}